// Round 1
// 233.292 us; speedup vs baseline: 1.0154x; 1.0154x over previous
//
#include <hip/hip_runtime.h>

// InputDefenseLayer: clip(x, -3.5, 3.5) then EMA scan along T (axis 1):
//   s_0 = xc_0 ; s_t = 0.25*xc_t + 0.75*s_{t-1}
// x: (B=64, T=2048, C=256) float32, contiguous, C innermost.
//
// R2 changes vs R1 (R1: 86 us/dispatch, 2.9 TB/s, VGPR=16 -> MLP-starved):
//  - float4 per lane (16 B loads/stores): 64 lanes = 1 wave per chunk-job.
//    4096 jobs -> 4096 waves (16/CU, grid-limited; we trade wave count for
//    bytes-in-flight per wave).
//  - Explicit depth-8 software pipeline with NAMED registers p0..p7 (no
//    runtime-indexed array -> stays in VGPRs). Steady state: 8 outstanding
//    dwordx4 loads/wave = 8 KiB/wave -> ~32 MB in flight device-wide,
//    vs ~4 MB in R1 (the cause of the 2.9 TB/s plateau).
//  - __launch_bounds__(256, 4): grid only fills 4 waves/SIMD anyway;
//    removes the VGPR cap that forced the compiler into load->wait->use.
//  - Warm-up + main loop merged into ONE fully-unrolled pipelined pass over
//    W+L=56 rows (store predicate row>=W folds at compile time). Numerics
//    identical to R1: seed at t0-W, W=24 -> error 7*0.75^24 ~= 7e-3.
//  - Non-temporal stores only (output never re-read); input loads stay
//    cached so the 128 MiB input remains L3-resident across iterations.

constexpr int B = 64;
constexpr int T = 2048;
constexpr int C = 256;
constexpr int L = 32;            // output chunk length along T
constexpr int W = 24;            // warm-up steps: 7*0.75^24 ~ 7e-3 < 7e-2
constexpr int NCHUNK = T / L;    // 64
constexpr int ROWF4 = C / 4;     // 64 float4 per t-row
constexpr int PF = 8;            // prefetch depth (software pipeline)

#define CLIP_LO -3.5f
#define CLIP_HI  3.5f
#define EMA_A 0.25f
#define EMA_B 0.75f

typedef float f4 __attribute__((ext_vector_type(4)));

__device__ __forceinline__ float clipf(float v) {
    return fminf(fmaxf(v, CLIP_LO), CLIP_HI);   // -> v_med3_f32
}

__device__ __forceinline__ f4 clip4(f4 v) {
    f4 r;
    r.x = clipf(v.x);
    r.y = clipf(v.y);
    r.z = clipf(v.z);
    r.w = clipf(v.w);
    return r;
}

__device__ __forceinline__ f4 ema4(f4 s, f4 v) {
    f4 r;
    r.x = fmaf(EMA_A, v.x, EMA_B * s.x);
    r.y = fmaf(EMA_A, v.y, EMA_B * s.y);
    r.z = fmaf(EMA_A, v.z, EMA_B * s.z);
    r.w = fmaf(EMA_A, v.w, EMA_B * s.w);
    return r;
}

// One pipeline slot: consume row (r+j) from p##j, then re-issue the load for
// row (r+j+PF) into the same named register. All guards fold after unroll
// (r, j, N, SKIP are compile-time under #pragma unroll).
#define SLOT(j)                                                              \
    if (r + j < N) {                                                         \
        f4 v = clip4(p##j);                                                  \
        s = (r + j == 0) ? v : ema4(s, v);                                   \
        if (r + j >= SKIP)                                                   \
            __builtin_nontemporal_store(s, op + (r + j) * ROWF4);            \
        if (r + j + PF < N)                                                  \
            p##j = xp[(r + j + PF) * ROWF4];                                 \
    }

// Process rows [0, N) of the window starting at xp/op (row stride ROWF4).
// Row 0 seeds the EMA state; rows >= SKIP are stored.
template <int N, int SKIP>
__device__ __forceinline__ void run_rows(const f4* __restrict__ xp,
                                         f4* __restrict__ op) {
    f4 p0 = xp[0 * ROWF4];
    f4 p1 = xp[1 * ROWF4];
    f4 p2 = xp[2 * ROWF4];
    f4 p3 = xp[3 * ROWF4];
    f4 p4 = xp[4 * ROWF4];
    f4 p5 = xp[5 * ROWF4];
    f4 p6 = xp[6 * ROWF4];
    f4 p7 = xp[7 * ROWF4];
    f4 s = {};
#pragma unroll
    for (int g = 0; g < (N + PF - 1) / PF; ++g) {
        const int r = g * PF;
        SLOT(0)
        SLOT(1)
        SLOT(2)
        SLOT(3)
        SLOT(4)
        SLOT(5)
        SLOT(6)
        SLOT(7)
    }
}

__global__ __launch_bounds__(256, 4) void ema_kernel(
    const float* __restrict__ x, float* __restrict__ out)
{
    // 4 chunk-jobs per 256-thread block; 64 float4-lanes (1 wave) each.
    const int job  = blockIdx.x * 4 + (threadIdx.x >> 6);
    const int lane = threadIdx.x & 63;
    const int b    = job >> 6;            // / NCHUNK
    const int k    = job & (NCHUNK - 1);  // % NCHUNK
    const int t0   = k * L;
    const int tb   = (k == 0) ? 0 : (t0 - W);

    const f4* __restrict__ xp = (const f4*)x + ((size_t)b * T + tb) * ROWF4 + lane;
    f4* __restrict__ op       = (f4*)out     + ((size_t)b * T + tb) * ROWF4 + lane;

    if (k == 0) {
        run_rows<L, 0>(xp, op);           // exact from t=0, store all 32 rows
    } else {
        run_rows<W + L, W>(xp, op);       // 24 warm-up rows, store last 32
    }
}

extern "C" void kernel_launch(void* const* d_in, const int* in_sizes, int n_in,
                              void* d_out, int out_size, void* d_ws, size_t ws_size,
                              hipStream_t stream) {
    const float* x = (const float*)d_in[0];
    float* out = (float*)d_out;
    const int n_jobs = B * NCHUNK;                 // 4096
    ema_kernel<<<dim3(n_jobs / 4), dim3(256), 0, stream>>>(x, out);
}